// Round 1
// baseline (842.081 us; speedup 1.0000x reference)
//
#include <hip/hip_runtime.h>

// Capsule routing, restructured to avoid materializing u_hat:
//   S[b,o,k]  = sum_n Wv[b,o,n] * u[b,n,k]          (537M MAC / iter)
//   vj[b,o,d] = sum_k S[b,o,k]  * W[k, o*64+d]      (33M MAC)
//   t[b,o,k]  = (1/nrm) sum_d vj[b,o,d] * W[k,o*64+d]
//   bb[b,o,n] = sum_k t[b,o,k] * u[b,n,k]           (537M MAC / iter)
// Total ~4.4 GFLOP vs 69 GFLOP naive; u (64MB) is the only big tensor (L3-hot).

constexpr int B = 32, N = 1024, K = 512, O = 32, D = 64, F = 2048;

// ---------------- softmax over o (axis=1), in place ----------------
__global__ void k_softmax(float* __restrict__ bb) {
  int idx = blockIdx.x * blockDim.x + threadIdx.x;  // over B*N columns
  int b = idx >> 10, n = idx & (N - 1);
  const size_t base = (size_t)b * O * N + n;
  float v[O];
  float m = -1e30f;
#pragma unroll
  for (int o = 0; o < O; o++) { v[o] = bb[base + (size_t)o * N]; m = fmaxf(m, v[o]); }
  float s = 0.f;
#pragma unroll
  for (int o = 0; o < O; o++) { v[o] = __expf(v[o] - m); s += v[o]; }
  float inv = 1.0f / s;
#pragma unroll
  for (int o = 0; o < O; o++) bb[base + (size_t)o * N] = v[o] * inv;
}

// ---------------- S[b,o,k] = sum_n Wv[b,o,n]*u[b,n,k] ----------------
// grid (B, K/64), 256 thr: kg=tid&63 (k), og=tid>>6 (8 o's each)
__global__ void k_S(const float* __restrict__ Wv, const float* __restrict__ u,
                    float* __restrict__ S) {
  __shared__ __align__(16) float wv_s[O][132];  // stride 132*4=528B, 16B-aligned rows
  int b = blockIdx.x, k0 = blockIdx.y * 64;
  int kg = threadIdx.x & 63, og = threadIdx.x >> 6;
  int k = k0 + kg;
  float acc[8] = {0.f, 0.f, 0.f, 0.f, 0.f, 0.f, 0.f, 0.f};
  const float* ub = u + (size_t)b * N * K + k;
  const float* wvb = Wv + (size_t)b * O * N;
  for (int nc = 0; nc < N; nc += 128) {
    __syncthreads();
    for (int i = threadIdx.x; i < O * 128; i += 256) {
      int o = i >> 7, nn = i & 127;
      wv_s[o][nn] = wvb[(size_t)o * N + nc + nn];
    }
    __syncthreads();
    for (int nn = 0; nn < 128; nn += 4) {
      float u0 = ub[(size_t)(nc + nn + 0) * K];
      float u1 = ub[(size_t)(nc + nn + 1) * K];
      float u2 = ub[(size_t)(nc + nn + 2) * K];
      float u3 = ub[(size_t)(nc + nn + 3) * K];
#pragma unroll
      for (int j = 0; j < 8; j++) {
        float4 w4 = *(const float4*)&wv_s[og * 8 + j][nn];  // broadcast, no conflict
        acc[j] += w4.x * u0 + w4.y * u1 + w4.z * u2 + w4.w * u3;
      }
    }
  }
#pragma unroll
  for (int j = 0; j < 8; j++)
    S[((size_t)b * O + og * 8 + j) * K + k] = acc[j];
}

// ------- vj[b,o,d] = sum_k S[b,o,k]*W[k,o*64+d]; mode<2: +sumsq, mode==2: squash->out
// grid (B, O/4), 256 thr: ol=tid>>6 (one o per wave), d=tid&63
__global__ void k_vj(const float* __restrict__ S, const float* __restrict__ W,
                     float* __restrict__ vj, float* __restrict__ sumsq,
                     float* __restrict__ out, int mode) {
  __shared__ __align__(16) float s_s[4][512];
  int b = blockIdx.x, og = blockIdx.y;
  int ol = threadIdx.x >> 6, d = threadIdx.x & 63;
  int o = og * 4 + ol;
  const float* Sb = S + ((size_t)b * O + og * 4) * K;
  for (int i = threadIdx.x; i < 4 * 512; i += 256) s_s[i >> 9][i & 511] = Sb[i];
  __syncthreads();
  float acc = 0.f;
  const float* Wc = W + (size_t)o * 64 + d;
  for (int k = 0; k < K; k += 4) {
    float4 s4 = *(const float4*)&s_s[ol][k];  // broadcast
    acc += s4.x * Wc[(size_t)k * F] + s4.y * Wc[(size_t)(k + 1) * F] +
           s4.z * Wc[(size_t)(k + 2) * F] + s4.w * Wc[(size_t)(k + 3) * F];
  }
  // per-(b,o) sum of squares across the wave (64 lanes)
  float ss = acc * acc;
#pragma unroll
  for (int m = 32; m >= 1; m >>= 1) ss += __shfl_xor(ss, m, 64);
  if (mode == 2) {
    float s = ss + 1e-7f;                 // squash: s = sum(vj^2)+eps
    float scale = sqrtf(s) / (0.5f + s);  // sqrt(s)/(0.5+s)
    out[((size_t)b * O + o) * D + d] = scale * acc;
  } else {
    vj[((size_t)b * O + o) * D + d] = acc;
    if (d == 0) atomicAdd(&sumsq[mode], ss);  // global L2 norm accumulator
  }
}

// ------- t[b,o,k] = (1/nrm) * sum_d vj[b,o,d]*W[k,o*64+d] -------
// grid B*O blocks, 256 thr, each thread 2 k's
__global__ void k_t(const float* __restrict__ vj, const float* __restrict__ W,
                    const float* __restrict__ sumsq, int slot, float* __restrict__ t) {
  __shared__ __align__(16) float vs[D];
  int bo = blockIdx.x;
  int o = bo & (O - 1);
  float nrm_inv = 1.0f / sqrtf(fmaxf(sumsq[slot], 1e-12f));
  if (threadIdx.x < D) vs[threadIdx.x] = vj[(size_t)bo * D + threadIdx.x] * nrm_inv;
  __syncthreads();
  for (int kk = threadIdx.x; kk < K; kk += 256) {
    const float4* Wp = (const float4*)(W + (size_t)kk * F + o * 64);
    float acc = 0.f;
#pragma unroll
    for (int d4 = 0; d4 < 16; d4++) {
      float4 w = Wp[d4];
      float4 v = *(const float4*)&vs[d4 * 4];
      acc += w.x * v.x + w.y * v.y + w.z * v.z + w.w * v.w;
    }
    t[(size_t)bo * K + kk] = acc;
  }
}

// ------- bb[b,o,n] = sum_k t[b,o,k]*u[b,n,k] -------
// grid (B, N/64), 256 thr: nl=tid&31 (2 n's), og=tid>>5 (4 o's) -> 2x4 reg tile
__global__ void k_bup(const float* __restrict__ t, const float* __restrict__ u,
                      float* __restrict__ bb) {
  __shared__ __align__(16) float u_s[64][66];  // stride 264B: float2-aligned, 2-way-free banks
  __shared__ __align__(16) float t_s[32][66];
  int b = blockIdx.x, n0 = blockIdx.y * 64;
  int nl = threadIdx.x & 31, og = threadIdx.x >> 5;
  float acc[2][4] = {{0.f, 0.f, 0.f, 0.f}, {0.f, 0.f, 0.f, 0.f}};
  const float* ub = u + ((size_t)b * N + n0) * K;
  const float* tb = t + (size_t)b * O * K;
  for (int kc = 0; kc < K; kc += 64) {
    __syncthreads();
    for (int i = threadIdx.x; i < 64 * 64; i += 256) {
      int nn = i >> 6, kk = i & 63;
      u_s[nn][kk] = ub[(size_t)nn * K + kc + kk];
    }
    for (int i = threadIdx.x; i < 32 * 64; i += 256) {
      int o = i >> 6, kk = i & 63;
      t_s[o][kk] = tb[(size_t)o * K + kc + kk];
    }
    __syncthreads();
    for (int kk = 0; kk < 64; kk += 2) {
      float2 u0 = *(const float2*)&u_s[nl][kk];
      float2 u1 = *(const float2*)&u_s[nl + 32][kk];
#pragma unroll
      for (int j = 0; j < 4; j++) {
        float2 tv = *(const float2*)&t_s[og * 4 + j][kk];  // broadcast per half-wave
        acc[0][j] += tv.x * u0.x + tv.y * u0.y;
        acc[1][j] += tv.x * u1.x + tv.y * u1.y;
      }
    }
  }
#pragma unroll
  for (int j = 0; j < 4; j++) {
    bb[((size_t)b * O + og * 4 + j) * N + n0 + nl] = acc[0][j];
    bb[((size_t)b * O + og * 4 + j) * N + n0 + nl + 32] = acc[1][j];
  }
}

extern "C" void kernel_launch(void* const* d_in, const int* in_sizes, int n_in,
                              void* d_out, int out_size, void* d_ws, size_t ws_size,
                              hipStream_t stream) {
  const float* u = (const float*)d_in[0];  // [B,N,K] f32
  const float* W = (const float*)d_in[1];  // [K,F] f32
  float* out = (float*)d_out;              // [B,O,D] f32

  float* ws = (float*)d_ws;
  float* S = ws;                           // B*O*K = 524288 (aliased with t)
  float* vj = S + (size_t)B * O * K;       // B*O*D = 65536
  float* bb = vj + (size_t)B * O * D;      // B*O*N = 1048576
  float* sumsq = bb + (size_t)B * O * N;   // 2 floats (one per norm step)
  float* t = S;                            // alias: S consumed before t written

  // zero bb (softmax of zeros -> uniform 1/32) and the two sumsq slots
  hipMemsetAsync(bb, 0, ((size_t)B * O * N + 2) * sizeof(float), stream);

  for (int i = 0; i < 3; i++) {
    k_softmax<<<B * N / 256, 256, 0, stream>>>(bb);
    k_S<<<dim3(B, K / 64), 256, 0, stream>>>(bb, u, S);
    k_vj<<<dim3(B, O / 4), 256, 0, stream>>>(S, W, vj, sumsq, out, i);
    if (i < 2) {
      k_t<<<B * O, 256, 0, stream>>>(vj, W, sumsq, i, t);
      k_bup<<<dim3(B, N / 64), 256, 0, stream>>>(t, u, bb);
    }
  }
}

// Round 2
// 419.846 us; speedup vs baseline: 2.0057x; 2.0057x over previous
//
#include <hip/hip_runtime.h>

// Capsule routing without materializing u_hat:
//   S[b,o,k]  = sum_n Wv[b,o,n] * u[b,n,k]          (537M MAC / iter)
//   vj[b,o,d] = sum_k S[b,o,k]  * W[k, o*64+d]
//   t[b,o,k]  = (1/nrm) sum_d vj[b,o,d] * W[k,o*64+d]
//   bb[b,o,n] = sum_k t[b,o,k] * u[b,n,k]           (537M MAC / iter)
// Iter 0 shortcut: softmax(0) is uniform -> S0[b,k] = colsum(u)/32, one row per b.
// k_S n-split 8x + fused softmax; fp32 atomics accumulate partials into zeroed S.

constexpr int B = 32, N = 1024, K = 512, O = 32, D = 64, F = 2048;

// colsum[b,k] = (1/32) sum_n u[b,n,k].  grid (B, N/32), 256 thr (k and k+256).
__global__ void k_colsum(const float* __restrict__ u, float* __restrict__ colsum) {
  int b = blockIdx.x, n0 = blockIdx.y * 32;
  int k1 = threadIdx.x, k2 = threadIdx.x + 256;
  const float* ub = u + (size_t)b * N * K + (size_t)n0 * K;
  float a1 = 0.f, a2 = 0.f;
#pragma unroll 4
  for (int nn = 0; nn < 32; nn++) {
    a1 += ub[(size_t)nn * K + k1];
    a2 += ub[(size_t)nn * K + k2];
  }
  atomicAdd(&colsum[b * K + k1], a1 * (1.f / 32.f));
  atomicAdd(&colsum[b * K + k2], a2 * (1.f / 32.f));
}

// S[b,o,k] += sum_{n in split} softmax_o(bb)[b,o,n] * u[b,n,k]
// grid (B, K/64, 8 n-splits), 256 thr: kg=tid&63, og=tid>>6 (8 o's each)
__global__ void k_S(const float* __restrict__ bb, const float* __restrict__ u,
                    float* __restrict__ S) {
  __shared__ __align__(16) float wv_s[O][132];
  int b = blockIdx.x, k0 = blockIdx.y * 64, n0 = blockIdx.z * 128;
  int kg = threadIdx.x & 63, og = threadIdx.x >> 6;
  // stage raw logits bb[b, :, n0..n0+128)
  const float* bbb = bb + (size_t)b * O * N + n0;
  for (int i = threadIdx.x; i < O * 128; i += 256) {
    int o = i >> 7, nn = i & 127;
    wv_s[o][nn] = bbb[(size_t)o * N + nn];
  }
  __syncthreads();
  // in-LDS softmax over o for each of the 128 columns
  if (threadIdx.x < 128) {
    int nn = threadIdx.x;
    float m = -1e30f;
#pragma unroll
    for (int o = 0; o < O; o++) m = fmaxf(m, wv_s[o][nn]);
    float s = 0.f;
#pragma unroll
    for (int o = 0; o < O; o++) s += __expf(wv_s[o][nn] - m);
    float inv = 1.0f / s;
#pragma unroll
    for (int o = 0; o < O; o++) wv_s[o][nn] = __expf(wv_s[o][nn] - m) * inv;
  }
  __syncthreads();
  float acc[8] = {};
  const float* ub = u + (size_t)b * N * K + (size_t)n0 * K + k0 + kg;
  for (int nn = 0; nn < 128; nn += 4) {
    float u0 = ub[(size_t)(nn + 0) * K];
    float u1 = ub[(size_t)(nn + 1) * K];
    float u2 = ub[(size_t)(nn + 2) * K];
    float u3 = ub[(size_t)(nn + 3) * K];
#pragma unroll
    for (int j = 0; j < 8; j++) {
      float4 w4 = *(const float4*)&wv_s[og * 8 + j][nn];  // wave-broadcast
      acc[j] += w4.x * u0 + w4.y * u1 + w4.z * u2 + w4.w * u3;
    }
  }
#pragma unroll
  for (int j = 0; j < 8; j++)
    atomicAdd(&S[((size_t)b * O + og * 8 + j) * K + k0 + kg], acc[j]);
}

// vj[b,o,d] = sum_k srow[k]*W[k,o*64+d]; srow = colsum row (mode 0) or S row.
// mode 0/1: write vj + atomic sumsq[mode]; mode 2: squash -> out.
// grid B*O blocks, 256 thr: d=tid&63, ks=tid>>6 (4-way k-split in block).
__global__ void k_vj(const float* __restrict__ S, const float* __restrict__ colsum,
                     const float* __restrict__ W, float* __restrict__ vj,
                     float* __restrict__ sumsq, float* __restrict__ out, int mode) {
  __shared__ __align__(16) float s_s[K];
  __shared__ float red[3][D];
  int bo = blockIdx.x, b = bo >> 5, o = bo & 31;
  int d = threadIdx.x & 63, ks = threadIdx.x >> 6;
  const float* src = (mode == 0) ? (colsum + (size_t)b * K) : (S + (size_t)bo * K);
  for (int i = threadIdx.x; i < K; i += 256) s_s[i] = src[i];
  __syncthreads();
  float acc = 0.f;
  const float* Wc = W + (size_t)o * D + d;
  for (int k = ks * 128; k < ks * 128 + 128; k += 4) {
    acc += s_s[k] * Wc[(size_t)k * F] + s_s[k + 1] * Wc[(size_t)(k + 1) * F] +
           s_s[k + 2] * Wc[(size_t)(k + 2) * F] + s_s[k + 3] * Wc[(size_t)(k + 3) * F];
  }
  if (ks) red[ks - 1][d] = acc;
  __syncthreads();
  if (ks == 0) {
    acc += red[0][d] + red[1][d] + red[2][d];
    float ss = acc * acc;
#pragma unroll
    for (int m = 32; m >= 1; m >>= 1) ss += __shfl_xor(ss, m, 64);
    if (mode == 2) {
      float s = ss + 1e-7f;
      out[(size_t)bo * D + d] = (sqrtf(s) / (0.5f + s)) * acc;
    } else {
      vj[(size_t)bo * D + d] = acc;
      if (d == 0) atomicAdd(&sumsq[mode], ss);
    }
  }
}

// t[b,o,k] = (1/nrm) sum_d vj[b,o,d]*W[k,o*64+d].  grid B*O, 256 thr.
__global__ void k_t(const float* __restrict__ vj, const float* __restrict__ W,
                    const float* __restrict__ sumsq, int slot, float* __restrict__ t) {
  __shared__ __align__(16) float vs[D];
  int bo = blockIdx.x;
  int o = bo & (O - 1);
  float nrm_inv = 1.0f / sqrtf(fmaxf(sumsq[slot], 1e-12f));
  if (threadIdx.x < D) vs[threadIdx.x] = vj[(size_t)bo * D + threadIdx.x] * nrm_inv;
  __syncthreads();
  for (int kk = threadIdx.x; kk < K; kk += 256) {
    const float4* Wp = (const float4*)(W + (size_t)kk * F + o * 64);
    float acc = 0.f;
#pragma unroll
    for (int d4 = 0; d4 < 16; d4++) {
      float4 w = Wp[d4];
      float4 v = *(const float4*)&vs[d4 * 4];
      acc += w.x * v.x + w.y * v.y + w.z * v.z + w.w * v.w;
    }
    t[(size_t)bo * K + kk] = acc;
  }
}

// bb[b,o,n] = sum_k t[b,o,k]*u[b,n,k].
// grid (B, N/32), 256 thr: nl=tid&31 (1 n), og=tid>>5 (4 o's) -> 4 outputs/thread
__global__ void k_bup(const float* __restrict__ t, const float* __restrict__ u,
                      float* __restrict__ bb) {
  __shared__ __align__(16) float u_s[32][68];  // 68: float4-aligned, bank-spread rows
  __shared__ __align__(16) float t_s[32][68];
  int b = blockIdx.x, n0 = blockIdx.y * 32;
  int nl = threadIdx.x & 31, og = threadIdx.x >> 5;
  float acc[4] = {};
  const float* ub = u + ((size_t)b * N + n0) * K;
  const float* tb = t + (size_t)b * O * K;
  for (int kc = 0; kc < K; kc += 64) {
    __syncthreads();
    for (int i = threadIdx.x; i < 32 * 64; i += 256) {
      int r = i >> 6, kk = i & 63;
      u_s[r][kk] = ub[(size_t)r * K + kc + kk];
      t_s[r][kk] = tb[(size_t)r * K + kc + kk];
    }
    __syncthreads();
    for (int kk = 0; kk < 64; kk += 4) {
      float4 u4 = *(const float4*)&u_s[nl][kk];
#pragma unroll
      for (int j = 0; j < 4; j++) {
        float4 t4 = *(const float4*)&t_s[og * 4 + j][kk];  // 2-addr/wave, free
        acc[j] += t4.x * u4.x + t4.y * u4.y + t4.z * u4.z + t4.w * u4.w;
      }
    }
  }
#pragma unroll
  for (int j = 0; j < 4; j++)
    bb[((size_t)b * O + og * 4 + j) * N + n0 + nl] = acc[j];
}

extern "C" void kernel_launch(void* const* d_in, const int* in_sizes, int n_in,
                              void* d_out, int out_size, void* d_ws, size_t ws_size,
                              hipStream_t stream) {
  const float* u = (const float*)d_in[0];  // [B,N,K] f32
  const float* W = (const float*)d_in[1];  // [K,F] f32
  float* out = (float*)d_out;              // [B,O,D] f32

  float* ws = (float*)d_ws;
  float* S = ws;                              // B*O*K = 524288
  float* colsum = S + (size_t)B * O * K;      // B*K = 16384
  float* vj = colsum + (size_t)B * K;         // B*O*D = 65536
  float* bbuf = vj + (size_t)B * O * D;       // B*O*N = 1048576
  float* sumsq = bbuf + (size_t)B * O * N;    // 2
  float* t = S;  // alias: S is dead by the time k_t writes (stream-ordered)

  hipMemsetAsync(colsum, 0, (size_t)B * K * sizeof(float), stream);
  hipMemsetAsync(sumsq, 0, 2 * sizeof(float), stream);

  // ---- iter 0 (uniform softmax shortcut) ----
  k_colsum<<<dim3(B, N / 32), 256, 0, stream>>>(u, colsum);
  k_vj<<<B * O, 256, 0, stream>>>(S, colsum, W, vj, sumsq, out, 0);
  k_t<<<B * O, 256, 0, stream>>>(vj, W, sumsq, 0, t);
  k_bup<<<dim3(B, N / 32), 256, 0, stream>>>(t, u, bbuf);

  // ---- iter 1 ----
  hipMemsetAsync(S, 0, (size_t)B * O * K * sizeof(float), stream);
  k_S<<<dim3(B, K / 64, 8), 256, 0, stream>>>(bbuf, u, S);
  k_vj<<<B * O, 256, 0, stream>>>(S, colsum, W, vj, sumsq, out, 1);
  k_t<<<B * O, 256, 0, stream>>>(vj, W, sumsq, 1, t);
  k_bup<<<dim3(B, N / 32), 256, 0, stream>>>(t, u, bbuf);

  // ---- iter 2 (squash -> out) ----
  hipMemsetAsync(S, 0, (size_t)B * O * K * sizeof(float), stream);
  k_S<<<dim3(B, K / 64, 8), 256, 0, stream>>>(bbuf, u, S);
  k_vj<<<B * O, 256, 0, stream>>>(S, colsum, W, vj, sumsq, out, 2);
}

// Round 3
// 359.683 us; speedup vs baseline: 2.3412x; 1.1673x over previous
//
#include <hip/hip_runtime.h>

// Capsule routing. u_hat never materialized; per routing iter:
//   vj = S@W_o ; t = (W_o@vjn)/nrm ; fused route: bb = t.u^T -> softmax -> S' = Wv.u
// Big GEMMs (bb, S') run on MFMA 16x16x32 bf16 with fp32 = hi+lo bf16 split
// (3 MFMAs, drop lo*lo: rel err ~1e-4). LDS-pipe pressure drops ~10x vs scalar.

constexpr int B = 32, N = 1024, K = 512, O = 32, D = 64, F = 2048;

typedef __attribute__((ext_vector_type(8))) short bf16x8;
typedef __attribute__((ext_vector_type(4))) float f32x4;

__device__ inline unsigned short bf16_rtn(float x) {
  unsigned int b = __float_as_uint(x);
  unsigned int r = b + 0x7FFFu + ((b >> 16) & 1u);
  return (unsigned short)(r >> 16);
}
__device__ inline void split2(float x, unsigned short& h, unsigned short& l) {
  h = bf16_rtn(x);
  l = bf16_rtn(x - __uint_as_float((unsigned int)h << 16));
}

// colsum[b,k] = (1/32) sum_n u[b,n,k]  (iter-0 shortcut: softmax(0) uniform)
// grid (B, 32): 32-n blocks; kq=4k per thread, 2 n-groups of 16 reduced via LDS.
__global__ __launch_bounds__(256) void k_colsum(const float* __restrict__ u,
                                                float* __restrict__ cs) {
  int b = blockIdx.x, n0 = blockIdx.y * 32;
  int kq = (threadIdx.x & 127) * 4, ng = threadIdx.x >> 7;
  const float* ub = u + ((size_t)b * N + n0 + ng * 16) * K + kq;
  float4 a = {0.f, 0.f, 0.f, 0.f};
#pragma unroll
  for (int r = 0; r < 16; r++) {
    float4 v = *(const float4*)&ub[(size_t)r * K];
    a.x += v.x; a.y += v.y; a.z += v.z; a.w += v.w;
  }
  __shared__ float4 red[128];
  if (ng) red[threadIdx.x & 127] = a;
  __syncthreads();
  if (!ng) {
    float4 o = red[threadIdx.x];
    atomicAdd(&cs[b * K + kq + 0], (a.x + o.x) * (1.f / 32.f));
    atomicAdd(&cs[b * K + kq + 1], (a.y + o.y) * (1.f / 32.f));
    atomicAdd(&cs[b * K + kq + 2], (a.z + o.z) * (1.f / 32.f));
    atomicAdd(&cs[b * K + kq + 3], (a.w + o.w) * (1.f / 32.f));
  }
}

// vj[b,o,d] = sum_k srow[k]*W[k,o*64+d]; srow = colsum (mode 0) or S row.
// mode 0/1: write vj + atomic global sumsq[mode]; mode 2: squash -> out.
__global__ __launch_bounds__(256) void k_vj(const float* __restrict__ S,
                                            const float* __restrict__ colsum,
                                            const float* __restrict__ W,
                                            float* __restrict__ vj,
                                            float* __restrict__ sumsq,
                                            float* __restrict__ out, int mode) {
  __shared__ __align__(16) float s_s[K];
  __shared__ float red[3][D];
  int bo = blockIdx.x, b = bo >> 5, o = bo & 31;
  int d = threadIdx.x & 63, ks = threadIdx.x >> 6;
  const float* src = (mode == 0) ? (colsum + (size_t)b * K) : (S + (size_t)bo * K);
  for (int i = threadIdx.x; i < K; i += 256) s_s[i] = src[i];
  __syncthreads();
  float acc = 0.f;
  const float* Wc = W + (size_t)o * D + d;
  for (int k = ks * 128; k < ks * 128 + 128; k += 4) {
    acc += s_s[k] * Wc[(size_t)k * F] + s_s[k + 1] * Wc[(size_t)(k + 1) * F] +
           s_s[k + 2] * Wc[(size_t)(k + 2) * F] + s_s[k + 3] * Wc[(size_t)(k + 3) * F];
  }
  if (ks) red[ks - 1][d] = acc;
  __syncthreads();
  if (ks == 0) {
    acc += red[0][d] + red[1][d] + red[2][d];
    float ss = acc * acc;
#pragma unroll
    for (int m = 32; m >= 1; m >>= 1) ss += __shfl_xor(ss, m, 64);
    if (mode == 2) {
      float s = ss + 1e-7f;
      out[(size_t)bo * D + d] = (sqrtf(s) / (0.5f + s)) * acc;
    } else {
      vj[(size_t)bo * D + d] = acc;
      if (d == 0) atomicAdd(&sumsq[mode], ss);
    }
  }
}

// t[b,o,k] = (1/nrm) sum_d vj[b,o,d]*W[k,o*64+d]; nrm = global L2 (axis=None!)
__global__ __launch_bounds__(256) void k_t(const float* __restrict__ vj,
                                           const float* __restrict__ W,
                                           const float* __restrict__ sumsq, int slot,
                                           float* __restrict__ t) {
  __shared__ __align__(16) float vs[D];
  int bo = blockIdx.x;
  int o = bo & (O - 1);
  float nrm_inv = 1.0f / sqrtf(fmaxf(sumsq[slot], 1e-12f));
  if (threadIdx.x < D) vs[threadIdx.x] = vj[(size_t)bo * D + threadIdx.x] * nrm_inv;
  __syncthreads();
  for (int kk = threadIdx.x; kk < K; kk += 256) {
    const float4* Wp = (const float4*)(W + (size_t)kk * F + o * 64);
    float acc = 0.f;
#pragma unroll
    for (int d4 = 0; d4 < 16; d4++) {
      float4 w = Wp[d4];
      float4 v = *(const float4*)&vs[d4 * 4];
      acc += w.x * v.x + w.y * v.y + w.z * v.z + w.w * v.w;
    }
    t[(size_t)bo * K + kk] = acc;
  }
}

// Fused routing step, MFMA 16x16x32 bf16 hi/lo split:
//  phase1: bb[32o][32n] = t[b].u[b,n-tile]^T   (K-loop over k=512)
//  softmax over o (in LDS), convert Wv to bf16 hi/lo
//  phase2: S[b] += Wv.u  (K-red = n = 32, one MFMA step; 32 k-tiles)
// grid (B, N/32) = 1024 blocks, 256 thr (4 waves, one 16x16 D-tile each in ph1).
constexpr int US = 96;  // LDS row stride (ushorts): 64 chunk + 32 pad -> 192B rows
__global__ __launch_bounds__(256) void k_route(const float* __restrict__ t,
                                               const float* __restrict__ u,
                                               float* __restrict__ S) {
  __shared__ unsigned short u_hi[32 * US], u_lo[32 * US];
  __shared__ unsigned short t_hi[32 * US], t_lo[32 * US];
  __shared__ float wv[O * 33];
  __shared__ unsigned short wv_hi[O * 40], wv_lo[O * 40];

  const int b = blockIdx.x, n0 = blockIdx.y * 32;
  const int tid = threadIdx.x;
  const int lane = tid & 63, wave = tid >> 6;
  const int m = lane & 15, oct = lane >> 4;
  const float* ub = u + ((size_t)b * N + n0) * K;
  const float* tb = t + (size_t)b * O * K;

  // ---- phase 1 ----
  const int mo = wave & 1, nt = wave >> 1;
  f32x4 accb = {0.f, 0.f, 0.f, 0.f};
  for (int kc = 0; kc < K; kc += 64) {
    __syncthreads();
    for (int i = tid; i < 512; i += 256) {
      int r = i >> 4, c = (i & 15) * 4;
      float4 uv = *(const float4*)&ub[(size_t)r * K + kc + c];
      float4 tv = *(const float4*)&tb[(size_t)r * K + kc + c];
      unsigned short h0, h1, h2, h3, l0, l1, l2, l3;
      split2(uv.x, h0, l0); split2(uv.y, h1, l1);
      split2(uv.z, h2, l2); split2(uv.w, h3, l3);
      uint2 ph, pl;
      ph.x = (unsigned)h0 | ((unsigned)h1 << 16); ph.y = (unsigned)h2 | ((unsigned)h3 << 16);
      pl.x = (unsigned)l0 | ((unsigned)l1 << 16); pl.y = (unsigned)l2 | ((unsigned)l3 << 16);
      *(uint2*)&u_hi[r * US + c] = ph;
      *(uint2*)&u_lo[r * US + c] = pl;
      split2(tv.x, h0, l0); split2(tv.y, h1, l1);
      split2(tv.z, h2, l2); split2(tv.w, h3, l3);
      ph.x = (unsigned)h0 | ((unsigned)h1 << 16); ph.y = (unsigned)h2 | ((unsigned)h3 << 16);
      pl.x = (unsigned)l0 | ((unsigned)l1 << 16); pl.y = (unsigned)l2 | ((unsigned)l3 << 16);
      *(uint2*)&t_hi[r * US + c] = ph;
      *(uint2*)&t_lo[r * US + c] = pl;
    }
    __syncthreads();
#pragma unroll
    for (int ks = 0; ks < 64; ks += 32) {
      bf16x8 ah = *(const bf16x8*)&t_hi[(mo * 16 + m) * US + ks + oct * 8];
      bf16x8 al = *(const bf16x8*)&t_lo[(mo * 16 + m) * US + ks + oct * 8];
      bf16x8 bh = *(const bf16x8*)&u_hi[(nt * 16 + m) * US + ks + oct * 8];
      bf16x8 bl = *(const bf16x8*)&u_lo[(nt * 16 + m) * US + ks + oct * 8];
      accb = __builtin_amdgcn_mfma_f32_16x16x32_bf16(ah, bh, accb, 0, 0, 0);
      accb = __builtin_amdgcn_mfma_f32_16x16x32_bf16(ah, bl, accb, 0, 0, 0);
      accb = __builtin_amdgcn_mfma_f32_16x16x32_bf16(al, bh, accb, 0, 0, 0);
    }
  }
  __syncthreads();
#pragma unroll
  for (int r = 0; r < 4; r++)  // C/D: col=lane&15, row=(lane>>4)*4+r
    wv[(mo * 16 + oct * 4 + r) * 33 + nt * 16 + m] = accb[r];
  __syncthreads();
  if (tid < 32) {  // softmax over o for column n=tid
    float mx = -1e30f;
    for (int o = 0; o < O; o++) mx = fmaxf(mx, wv[o * 33 + tid]);
    float s = 0.f;
    for (int o = 0; o < O; o++) { float e = __expf(wv[o * 33 + tid] - mx); wv[o * 33 + tid] = e; s += e; }
    float inv = 1.f / s;
    for (int o = 0; o < O; o++) wv[o * 33 + tid] *= inv;
  }
  __syncthreads();
  for (int i = tid; i < O * 32; i += 256) {
    int o = i >> 5, n = i & 31;
    unsigned short h, l;
    split2(wv[o * 33 + n], h, l);
    wv_hi[o * 40 + n] = h;
    wv_lo[o * 40 + n] = l;
  }
  __syncthreads();

  // ---- phase 2 ----
  const int mo2 = wave & 1, kt0 = (wave >> 1) * 16;
  bf16x8 a2h = *(const bf16x8*)&wv_hi[(mo2 * 16 + m) * 40 + oct * 8];
  bf16x8 a2l = *(const bf16x8*)&wv_lo[(mo2 * 16 + m) * 40 + oct * 8];
  float* Sb = S + (size_t)b * O * K;
  for (int kt = kt0; kt < kt0 + 16; kt++) {
    int kcol = kt * 16 + m;
    bf16x8 bh, bl;
#pragma unroll
    for (int j = 0; j < 8; j++) {  // B[n=oct*8+j][kcol], u re-read (L2-hot)
      float x = ub[(size_t)(oct * 8 + j) * K + kcol];
      unsigned short h, l;
      split2(x, h, l);
      bh[j] = (short)h;
      bl[j] = (short)l;
    }
    f32x4 acs = {0.f, 0.f, 0.f, 0.f};
    acs = __builtin_amdgcn_mfma_f32_16x16x32_bf16(a2h, bh, acs, 0, 0, 0);
    acs = __builtin_amdgcn_mfma_f32_16x16x32_bf16(a2h, bl, acs, 0, 0, 0);
    acs = __builtin_amdgcn_mfma_f32_16x16x32_bf16(a2l, bh, acs, 0, 0, 0);
#pragma unroll
    for (int r = 0; r < 4; r++)
      atomicAdd(&Sb[(size_t)(mo2 * 16 + oct * 4 + r) * K + kcol], acs[r]);
  }
}

extern "C" void kernel_launch(void* const* d_in, const int* in_sizes, int n_in,
                              void* d_out, int out_size, void* d_ws, size_t ws_size,
                              hipStream_t stream) {
  const float* u = (const float*)d_in[0];  // [B,N,K] f32
  const float* W = (const float*)d_in[1];  // [K,F] f32
  float* out = (float*)d_out;              // [B,O,D] f32

  float* ws = (float*)d_ws;
  float* S1 = ws;                             // B*O*K
  float* S2 = S1 + (size_t)B * O * K;         // B*O*K
  float* colsum = S2 + (size_t)B * O * K;     // B*K
  float* sumsq = colsum + (size_t)B * K;      // 16 (2 used)
  float* vj = sumsq + 16;                     // B*O*D
  float* t = vj + (size_t)B * O * D;          // B*O*K

  // one contiguous zero: S1 | S2 | colsum | sumsq
  hipMemsetAsync(S1, 0, ((size_t)2 * B * O * K + B * K + 16) * sizeof(float), stream);

  // iter 0 (uniform softmax shortcut)
  k_colsum<<<dim3(B, 32), 256, 0, stream>>>(u, colsum);
  k_vj<<<B * O, 256, 0, stream>>>(S1, colsum, W, vj, sumsq, out, 0);
  k_t<<<B * O, 256, 0, stream>>>(vj, W, sumsq, 0, t);
  k_route<<<dim3(B, N / 32), 256, 0, stream>>>(t, u, S1);
  // iter 1
  k_vj<<<B * O, 256, 0, stream>>>(S1, colsum, W, vj, sumsq, out, 1);
  k_t<<<B * O, 256, 0, stream>>>(vj, W, sumsq, 1, t);
  k_route<<<dim3(B, N / 32), 256, 0, stream>>>(t, u, S2);
  // iter 2 (squash -> out)
  k_vj<<<B * O, 256, 0, stream>>>(S2, colsum, W, vj, sumsq, out, 2);
}

// Round 4
// 262.344 us; speedup vs baseline: 3.2098x; 1.3710x over previous
//
#include <hip/hip_runtime.h>

// Capsule routing; u_hat never materialized. Per iter:
//   vjt: vj = S@W_o (regs) -> sumsq atomic; t = W_o@vj (UNNORMALIZED)
//   route: bb = (t.u^T)/nrm -> softmax_o -> S' += Wv.u   (MFMA bf16 hi/lo split)
// Iter-0: softmax(0) uniform -> colsum shortcut. 1/nrm applied to bb logits
// (identical algebra), so t needs no norm and vj+t fuse into one kernel.

constexpr int B = 32, N = 1024, K = 512, O = 32, D = 64, F = 2048;
constexpr int ST = 72;  // LDS u16 stride: 144B rows -> dword-stride 36 (2-way-free b128)

typedef __attribute__((ext_vector_type(8))) short bf16x8;
typedef __attribute__((ext_vector_type(4))) float f32x4;

__device__ inline unsigned short bf16_rtn(float x) {
  unsigned int b = __float_as_uint(x);
  return (unsigned short)((b + 0x7FFFu + ((b >> 16) & 1u)) >> 16);
}
__device__ inline void split2(float x, unsigned short& h, unsigned short& l) {
  h = bf16_rtn(x);
  l = bf16_rtn(x - __uint_as_float((unsigned int)h << 16));
}
__device__ inline void pack4(float4 v, uint2& ph, uint2& pl) {
  unsigned short h0, h1, h2, h3, l0, l1, l2, l3;
  split2(v.x, h0, l0); split2(v.y, h1, l1);
  split2(v.z, h2, l2); split2(v.w, h3, l3);
  ph.x = (unsigned)h0 | ((unsigned)h1 << 16); ph.y = (unsigned)h2 | ((unsigned)h3 << 16);
  pl.x = (unsigned)l0 | ((unsigned)l1 << 16); pl.y = (unsigned)l2 | ((unsigned)l3 << 16);
}

// colsum[b,k] = (1/32) sum_n u[b,n,k]
__global__ __launch_bounds__(256) void k_colsum(const float* __restrict__ u,
                                                float* __restrict__ cs) {
  int b = blockIdx.x, n0 = blockIdx.y * 32;
  int kq = (threadIdx.x & 127) * 4, ng = threadIdx.x >> 7;
  const float* ub = u + ((size_t)b * N + n0 + ng * 16) * K + kq;
  float4 a = {0.f, 0.f, 0.f, 0.f};
#pragma unroll
  for (int r = 0; r < 16; r++) {
    float4 v = *(const float4*)&ub[(size_t)r * K];
    a.x += v.x; a.y += v.y; a.z += v.z; a.w += v.w;
  }
  __shared__ float4 red[128];
  if (ng) red[threadIdx.x & 127] = a;
  __syncthreads();
  if (!ng) {
    float4 o = red[threadIdx.x];
    atomicAdd(&cs[b * K + kq + 0], (a.x + o.x) * (1.f / 32.f));
    atomicAdd(&cs[b * K + kq + 1], (a.y + o.y) * (1.f / 32.f));
    atomicAdd(&cs[b * K + kq + 2], (a.z + o.z) * (1.f / 32.f));
    atomicAdd(&cs[b * K + kq + 3], (a.w + o.w) * (1.f / 32.f));
  }
}

// Fused vj+t per (b,o): vj[d]=sum_k s[k]W[k,o*64+d] (regs+LDS), sumsq atomic,
// then t[k] = sum_d vj[d]*W[k,o*64+d] (unnormalized).
__global__ __launch_bounds__(256) void k_vjt(const float* __restrict__ S,
                                             const float* __restrict__ colsum,
                                             const float* __restrict__ W,
                                             float* __restrict__ sumsq, int slot,
                                             float* __restrict__ t) {
  __shared__ __align__(16) float s_s[K];
  __shared__ float red[3][D];
  __shared__ __align__(16) float vs[D];
  int bo = blockIdx.x, b = bo >> 5, o = bo & 31;
  int d = threadIdx.x & 63, ks = threadIdx.x >> 6;
  const float* src = (slot == 0) ? (colsum + (size_t)b * K) : (S + (size_t)bo * K);
  for (int i = threadIdx.x; i < K; i += 256) s_s[i] = src[i];
  __syncthreads();
  float acc = 0.f;
  const float* Wc = W + (size_t)o * D + d;
  for (int k = ks * 128; k < ks * 128 + 128; k += 4) {
    acc += s_s[k] * Wc[(size_t)k * F] + s_s[k + 1] * Wc[(size_t)(k + 1) * F] +
           s_s[k + 2] * Wc[(size_t)(k + 2) * F] + s_s[k + 3] * Wc[(size_t)(k + 3) * F];
  }
  if (ks) red[ks - 1][d] = acc;
  __syncthreads();
  if (ks == 0) {
    acc += red[0][d] + red[1][d] + red[2][d];
    vs[d] = acc;
    float ss = acc * acc;
#pragma unroll
    for (int m = 32; m >= 1; m >>= 1) ss += __shfl_xor(ss, m, 64);
    if (d == 0) atomicAdd(&sumsq[slot], ss);
  }
  __syncthreads();
  for (int kk = threadIdx.x; kk < K; kk += 256) {
    const float4* Wp = (const float4*)(W + (size_t)kk * F + o * 64);
    float a = 0.f;
#pragma unroll
    for (int d4 = 0; d4 < 16; d4++) {
      float4 w = Wp[d4];
      float4 v = *(const float4*)&vs[d4 * 4];
      a += w.x * v.x + w.y * v.y + w.z * v.z + w.w * v.w;
    }
    t[(size_t)bo * K + kk] = a;
  }
}

// Final: vj from S row -> squash -> out
__global__ __launch_bounds__(256) void k_out(const float* __restrict__ S,
                                             const float* __restrict__ W,
                                             float* __restrict__ out) {
  __shared__ __align__(16) float s_s[K];
  __shared__ float red[3][D];
  int bo = blockIdx.x, o = bo & 31;
  int d = threadIdx.x & 63, ks = threadIdx.x >> 6;
  const float* src = S + (size_t)bo * K;
  for (int i = threadIdx.x; i < K; i += 256) s_s[i] = src[i];
  __syncthreads();
  float acc = 0.f;
  const float* Wc = W + (size_t)o * D + d;
  for (int k = ks * 128; k < ks * 128 + 128; k += 4) {
    acc += s_s[k] * Wc[(size_t)k * F] + s_s[k + 1] * Wc[(size_t)(k + 1) * F] +
           s_s[k + 2] * Wc[(size_t)(k + 2) * F] + s_s[k + 3] * Wc[(size_t)(k + 3) * F];
  }
  if (ks) red[ks - 1][d] = acc;
  __syncthreads();
  if (ks == 0) {
    acc += red[0][d] + red[1][d] + red[2][d];
    float ss = acc * acc;
#pragma unroll
    for (int m = 32; m >= 1; m >>= 1) ss += __shfl_xor(ss, m, 64);
    float s = ss + 1e-7f;
    out[(size_t)bo * D + d] = (sqrtf(s) / (0.5f + s)) * acc;
  }
}

// Fused routing step, 64-n tile, 512 threads (8 waves), MFMA 16x16x32 bf16.
// phase1: bb[32o][64n] = (t . u_tile^T)/nrm ; softmax over o ; bf16-split Wv
// phase2: S[b] += Wv . u_tile  (per 64-kcol chunk: transposed-u LDS restage)
__global__ __launch_bounds__(512, 2) void k_route(const float* __restrict__ t,
                                                  const float* __restrict__ u,
                                                  const float* __restrict__ sumsq,
                                                  int slot, float* __restrict__ S) {
  __shared__ __align__(16) char smem[36352];
  unsigned short* u_hi = (unsigned short*)smem;            // [64][ST] phase1 u chunk
  unsigned short* u_lo = u_hi + 64 * ST;
  unsigned short* t_hi = (unsigned short*)(smem + 18432);  // [32][ST] phase1 t chunk
  unsigned short* t_lo = t_hi + 32 * ST;
  float* wv = (float*)(smem + 18432 + 9216);               // [32][68] logits/softmax
  unsigned short* wvh = t_hi;  // alias: t dead after phase-1
  unsigned short* wvl = t_lo;
  unsigned short* uTh = u_hi;  // alias: phase-2 transposed u chunk [64kcol][ST(n)]
  unsigned short* uTl = u_lo;

  const int b = blockIdx.x, n0 = blockIdx.y * 64;
  const int tid = threadIdx.x, lane = tid & 63, wave = tid >> 6;
  const int m = lane & 15, oct = lane >> 4;
  const float* ub = u + ((size_t)b * N + n0) * K;
  const float* tb = t + (size_t)b * O * K;
  const float nrm_inv = rsqrtf(fmaxf(sumsq[slot], 1e-12f));

  // ---- phase 1: bb = t . u^T ----
  const int mo = wave & 1, nt = wave >> 1;  // o-tile, n-tile (16x16 each)
  f32x4 accb = {0.f, 0.f, 0.f, 0.f};
  for (int kc = 0; kc < K; kc += 64) {
    __syncthreads();
    {  // stage t (512 f4, 1/thread) and u (1024 f4, 2/thread)
      int r = tid >> 4, c4 = (tid & 15) * 4;
      float4 tv = *(const float4*)&tb[(size_t)r * K + kc + c4];
      uint2 ph, pl;
      pack4(tv, ph, pl);
      *(uint2*)&t_hi[r * ST + c4] = ph;
      *(uint2*)&t_lo[r * ST + c4] = pl;
#pragma unroll
      for (int h = 0; h < 2; h++) {
        int i = tid + h * 512;
        int ur = i >> 4, uc = (i & 15) * 4;
        float4 uv = *(const float4*)&ub[(size_t)ur * K + kc + uc];
        pack4(uv, ph, pl);
        *(uint2*)&u_hi[ur * ST + uc] = ph;
        *(uint2*)&u_lo[ur * ST + uc] = pl;
      }
    }
    __syncthreads();
#pragma unroll
    for (int ks = 0; ks < 64; ks += 32) {
      bf16x8 ah = *(const bf16x8*)&t_hi[(mo * 16 + m) * ST + ks + oct * 8];
      bf16x8 al = *(const bf16x8*)&t_lo[(mo * 16 + m) * ST + ks + oct * 8];
      bf16x8 bh = *(const bf16x8*)&u_hi[(nt * 16 + m) * ST + ks + oct * 8];
      bf16x8 bl = *(const bf16x8*)&u_lo[(nt * 16 + m) * ST + ks + oct * 8];
      accb = __builtin_amdgcn_mfma_f32_16x16x32_bf16(ah, bh, accb, 0, 0, 0);
      accb = __builtin_amdgcn_mfma_f32_16x16x32_bf16(ah, bl, accb, 0, 0, 0);
      accb = __builtin_amdgcn_mfma_f32_16x16x32_bf16(al, bh, accb, 0, 0, 0);
    }
  }
  __syncthreads();
#pragma unroll
  for (int r = 0; r < 4; r++)  // D: col=lane&15 (n), row=oct*4+r (o); scale by 1/nrm
    wv[(mo * 16 + oct * 4 + r) * 68 + nt * 16 + m] = accb[r] * nrm_inv;
  __syncthreads();
  if (tid < 64) {  // softmax over o, column n=tid
    float mx = -1e30f;
    for (int o = 0; o < O; o++) mx = fmaxf(mx, wv[o * 68 + tid]);
    float s = 0.f;
    for (int o = 0; o < O; o++) { float e = __expf(wv[o * 68 + tid] - mx); wv[o * 68 + tid] = e; s += e; }
    float inv = 1.f / s;
    for (int o = 0; o < O; o++) wv[o * 68 + tid] *= inv;
  }
  __syncthreads();
  for (int i = tid; i < O * 64; i += 512) {  // Wv -> bf16 hi/lo [o][ST]
    int o = i >> 6, n = i & 63;
    unsigned short h, l;
    split2(wv[o * 68 + n], h, l);
    wvh[o * ST + n] = h;
    wvl[o * ST + n] = l;
  }
  __syncthreads();

  // ---- phase 2: S += Wv . u  (k-red = n = 64 -> 2 MFMA steps) ----
  const int otile = wave & 1, ktile = wave >> 1;
  const int o0 = otile * 16;
  bf16x8 a0h = *(const bf16x8*)&wvh[(o0 + m) * ST + oct * 8];
  bf16x8 a0l = *(const bf16x8*)&wvl[(o0 + m) * ST + oct * 8];
  bf16x8 a1h = *(const bf16x8*)&wvh[(o0 + m) * ST + 32 + oct * 8];
  bf16x8 a1l = *(const bf16x8*)&wvl[(o0 + m) * ST + 32 + oct * 8];
  float* Sb = S + (size_t)b * O * K;
  for (int kc = 0; kc < K; kc += 64) {
    __syncthreads();
    for (int i = tid; i < 1024; i += 512) {  // restage transposed (L2-hot re-read)
      int r = i >> 4, c4 = (i & 15) * 4;
      float4 v = *(const float4*)&ub[(size_t)r * K + kc + c4];
      unsigned short h, l;
      split2(v.x, h, l); uTh[(c4 + 0) * ST + r] = h; uTl[(c4 + 0) * ST + r] = l;
      split2(v.y, h, l); uTh[(c4 + 1) * ST + r] = h; uTl[(c4 + 1) * ST + r] = l;
      split2(v.z, h, l); uTh[(c4 + 2) * ST + r] = h; uTl[(c4 + 2) * ST + r] = l;
      split2(v.w, h, l); uTh[(c4 + 3) * ST + r] = h; uTl[(c4 + 3) * ST + r] = l;
    }
    __syncthreads();
    f32x4 acs = {0.f, 0.f, 0.f, 0.f};
    bf16x8 bh = *(const bf16x8*)&uTh[(ktile * 16 + m) * ST + oct * 8];
    bf16x8 bl = *(const bf16x8*)&uTl[(ktile * 16 + m) * ST + oct * 8];
    acs = __builtin_amdgcn_mfma_f32_16x16x32_bf16(a0h, bh, acs, 0, 0, 0);
    acs = __builtin_amdgcn_mfma_f32_16x16x32_bf16(a0h, bl, acs, 0, 0, 0);
    acs = __builtin_amdgcn_mfma_f32_16x16x32_bf16(a0l, bh, acs, 0, 0, 0);
    bh = *(const bf16x8*)&uTh[(ktile * 16 + m) * ST + 32 + oct * 8];
    bl = *(const bf16x8*)&uTl[(ktile * 16 + m) * ST + 32 + oct * 8];
    acs = __builtin_amdgcn_mfma_f32_16x16x32_bf16(a1h, bh, acs, 0, 0, 0);
    acs = __builtin_amdgcn_mfma_f32_16x16x32_bf16(a1h, bl, acs, 0, 0, 0);
    acs = __builtin_amdgcn_mfma_f32_16x16x32_bf16(a1l, bh, acs, 0, 0, 0);
#pragma unroll
    for (int r = 0; r < 4; r++)  // D: col=m -> kcol, row=oct*4+r -> o
      atomicAdd(&Sb[(size_t)(o0 + oct * 4 + r) * K + kc + ktile * 16 + m], acs[r]);
  }
}

extern "C" void kernel_launch(void* const* d_in, const int* in_sizes, int n_in,
                              void* d_out, int out_size, void* d_ws, size_t ws_size,
                              hipStream_t stream) {
  const float* u = (const float*)d_in[0];  // [B,N,K] f32
  const float* W = (const float*)d_in[1];  // [K,F] f32
  float* out = (float*)d_out;              // [B,O,D] f32

  float* ws = (float*)d_ws;
  float* S1 = ws;                           // B*O*K
  float* S2 = S1 + (size_t)B * O * K;       // B*O*K
  float* colsum = S2 + (size_t)B * O * K;   // B*K
  float* sumsq = colsum + (size_t)B * K;    // 16 (2 used)
  float* t = sumsq + 16;                    // B*O*K

  // zero S1|S2|colsum|sumsq in one shot
  hipMemsetAsync(S1, 0, ((size_t)2 * B * O * K + B * K + 16) * sizeof(float), stream);

  k_colsum<<<dim3(B, 32), 256, 0, stream>>>(u, colsum);
  k_vjt<<<B * O, 256, 0, stream>>>(S1, colsum, W, sumsq, 0, t);   // iter0 (uniform)
  k_route<<<dim3(B, N / 64), 512, 0, stream>>>(t, u, sumsq, 0, S1);
  k_vjt<<<B * O, 256, 0, stream>>>(S1, colsum, W, sumsq, 1, t);   // iter1
  k_route<<<dim3(B, N / 64), 512, 0, stream>>>(t, u, sumsq, 1, S2);
  k_out<<<B * O, 256, 0, stream>>>(S2, W, out);                   // iter2 + squash
}

// Round 5
// 257.120 us; speedup vs baseline: 3.2750x; 1.0203x over previous
//
#include <hip/hip_runtime.h>
#include <hip/hip_bf16.h>

// Capsule routing; u_hat never materialized. Per iter:
//   vjt: vj = S@W_o -> global sumsq; t = W_o@vj (UNNORMALIZED)
//   route: bb = (t.u^T)/nrm -> softmax_o -> S' += Wv.u   (MFMA 16x16x32 bf16)
// fp32 via bf16 hi/lo split on t and Wv only; u is single bf16 (err ~2^-9).
// u staged once per chunk in [n][k] layout with 8-col XOR swizzle so BOTH
// row-major (phase1 b128) and column-strided (phase2 B-frag) reads are cheap.

constexpr int B = 32, N = 1024, K = 512, O = 32, D = 64, F = 2048;
constexpr int ST = 72;  // u16 row stride: 144B, 16B-aligned for b128 row reads

typedef __attribute__((ext_vector_type(8))) short bf16x8;
typedef __attribute__((ext_vector_type(4))) float f32x4;

__device__ inline unsigned int pk_hi(float x, float y) {
  union { __hip_bfloat162 h; unsigned int u; } c;
  c.h = __float22bfloat162_rn(float2{x, y});
  return c.u;
}
__device__ inline void unpk(unsigned int p, float& fx, float& fy) {
  fx = __uint_as_float(p << 16);
  fy = __uint_as_float(p & 0xffff0000u);
}
__device__ inline int swz(int r) { return ((r >> 3) & 7) << 3; }

// store 4 hi-bf16 at [r][c4] (c4 mult of 4), 8-block XOR swizzled
__device__ inline void stage_hi(unsigned short* hi, int r, int c4, float4 v) {
  int c = c4 ^ swz(r);
  uint2 p;
  p.x = pk_hi(v.x, v.y);
  p.y = pk_hi(v.z, v.w);
  *(uint2*)&hi[r * ST + c] = p;
}
__device__ inline void stage_hilo(unsigned short* hi, unsigned short* lo, int r,
                                  int c4, float4 v) {
  int c = c4 ^ swz(r);
  uint2 ph, pl;
  ph.x = pk_hi(v.x, v.y);
  ph.y = pk_hi(v.z, v.w);
  float ax, ay, az, aw;
  unpk(ph.x, ax, ay);
  unpk(ph.y, az, aw);
  pl.x = pk_hi(v.x - ax, v.y - ay);
  pl.y = pk_hi(v.z - az, v.w - aw);
  *(uint2*)&hi[r * ST + c] = ph;
  *(uint2*)&lo[r * ST + c] = pl;
}
// row-major frag (phase1): 8 consecutive k at row r, k0 mult of 8
__device__ inline bf16x8 frag_row(const unsigned short* p, int r, int k0) {
  return *(const bf16x8*)&p[r * ST + (k0 ^ swz(r))];
}
// column frag (phase2 B): lane's kcol, 8 consecutive n from n0
__device__ inline bf16x8 frag_col(const unsigned short* p, int kcol, int n0) {
  bf16x8 f;
#pragma unroll
  for (int j = 0; j < 8; j++) {
    int n = n0 + j;
    f[j] = (short)p[n * ST + (kcol ^ swz(n))];
  }
  return f;
}

// colsum[b,k] = (1/32) sum_n u[b,n,k]  (iter-0: softmax(0) uniform)
__global__ __launch_bounds__(256) void k_colsum(const float* __restrict__ u,
                                                float* __restrict__ cs) {
  int b = blockIdx.x, n0 = blockIdx.y * 32;
  int kq = (threadIdx.x & 127) * 4, ng = threadIdx.x >> 7;
  const float* ub = u + ((size_t)b * N + n0 + ng * 16) * K + kq;
  float4 a = {0.f, 0.f, 0.f, 0.f};
#pragma unroll
  for (int r = 0; r < 16; r++) {
    float4 v = *(const float4*)&ub[(size_t)r * K];
    a.x += v.x; a.y += v.y; a.z += v.z; a.w += v.w;
  }
  __shared__ float4 red[128];
  if (ng) red[threadIdx.x & 127] = a;
  __syncthreads();
  if (!ng) {
    float4 o = red[threadIdx.x];
    atomicAdd(&cs[b * K + kq + 0], (a.x + o.x) * (1.f / 32.f));
    atomicAdd(&cs[b * K + kq + 1], (a.y + o.y) * (1.f / 32.f));
    atomicAdd(&cs[b * K + kq + 2], (a.z + o.z) * (1.f / 32.f));
    atomicAdd(&cs[b * K + kq + 3], (a.w + o.w) * (1.f / 32.f));
  }
}

// vj[d]=sum_k s[k]W[k,o*64+d] -> sumsq atomic; t[k]=sum_d vj[d]W[k,o*64+d]
__global__ __launch_bounds__(512) void k_vjt(const float* __restrict__ S,
                                             const float* __restrict__ colsum,
                                             const float* __restrict__ W,
                                             float* __restrict__ sumsq, int slot,
                                             float* __restrict__ t) {
  __shared__ __align__(16) float s_s[K];
  __shared__ float red[7][D];
  __shared__ __align__(16) float vs[D];
  int bo = blockIdx.x, b = bo >> 5, o = bo & 31;
  int d = threadIdx.x & 63, ks = threadIdx.x >> 6;  // 8-way k split
  const float* src = (slot == 0) ? (colsum + (size_t)b * K) : (S + (size_t)bo * K);
  for (int i = threadIdx.x; i < K; i += 512) s_s[i] = src[i];
  __syncthreads();
  float acc = 0.f;
  const float* Wc = W + (size_t)o * D + d;
  for (int k = ks * 64; k < ks * 64 + 64; k += 4) {
    acc += s_s[k] * Wc[(size_t)k * F] + s_s[k + 1] * Wc[(size_t)(k + 1) * F] +
           s_s[k + 2] * Wc[(size_t)(k + 2) * F] + s_s[k + 3] * Wc[(size_t)(k + 3) * F];
  }
  if (ks) red[ks - 1][d] = acc;
  __syncthreads();
  if (ks == 0) {
#pragma unroll
    for (int j = 0; j < 7; j++) acc += red[j][d];
    vs[d] = acc;
    float ss = acc * acc;
#pragma unroll
    for (int m = 32; m >= 1; m >>= 1) ss += __shfl_xor(ss, m, 64);
    if (d == 0) atomicAdd(&sumsq[slot], ss);
  }
  __syncthreads();
  {
    int kk = threadIdx.x;  // 512 threads = 512 rows, one each
    const float4* Wp = (const float4*)(W + (size_t)kk * F + o * 64);
    float a = 0.f;
#pragma unroll
    for (int d4 = 0; d4 < 16; d4++) {
      float4 w = Wp[d4];
      float4 v = *(const float4*)&vs[d4 * 4];
      a += w.x * v.x + w.y * v.y + w.z * v.z + w.w * v.w;
    }
    t[(size_t)bo * K + kk] = a;
  }
}

// Final: vj from S row -> squash -> out
__global__ __launch_bounds__(512) void k_out(const float* __restrict__ S,
                                             const float* __restrict__ W,
                                             float* __restrict__ out) {
  __shared__ __align__(16) float s_s[K];
  __shared__ float red[7][D];
  int bo = blockIdx.x, o = bo & 31;
  int d = threadIdx.x & 63, ks = threadIdx.x >> 6;
  const float* src = S + (size_t)bo * K;
  for (int i = threadIdx.x; i < K; i += 512) s_s[i] = src[i];
  __syncthreads();
  float acc = 0.f;
  const float* Wc = W + (size_t)o * D + d;
  for (int k = ks * 64; k < ks * 64 + 64; k += 4) {
    acc += s_s[k] * Wc[(size_t)k * F] + s_s[k + 1] * Wc[(size_t)(k + 1) * F] +
           s_s[k + 2] * Wc[(size_t)(k + 2) * F] + s_s[k + 3] * Wc[(size_t)(k + 3) * F];
  }
  if (ks) red[ks - 1][d] = acc;
  __syncthreads();
  if (ks == 0) {
#pragma unroll
    for (int j = 0; j < 7; j++) acc += red[j][d];
    float ss = acc * acc;
#pragma unroll
    for (int m = 32; m >= 1; m >>= 1) ss += __shfl_xor(ss, m, 64);
    float s = ss + 1e-7f;
    out[(size_t)bo * D + d] = (sqrtf(s) / (0.5f + s)) * acc;
  }
}

// Fused routing step, 64-n tile, 512 thr (8 waves).
// phase1: bb[32o][64n] = (t.u^T)/nrm ; softmax over o ; Wv -> bf16 hi/lo
// phase2: S[b] += Wv.u  (B-frag via swizzled column reads; no transpose)
__global__ __launch_bounds__(512, 2) void k_route(const float* __restrict__ t,
                                                  const float* __restrict__ u,
                                                  const float* __restrict__ sumsq,
                                                  int slot, float* __restrict__ S) {
  __shared__ unsigned short u_hi[64 * ST];                  // 9216 B
  __shared__ unsigned short t_hi[32 * ST], t_lo[32 * ST];   // 2x4608 B
  __shared__ float wv[O * 68];                              // 8704 B
  unsigned short* wvh = t_hi;  // alias: t dead after phase 1
  unsigned short* wvl = t_lo;

  const int b = blockIdx.x, n0 = blockIdx.y * 64;
  const int tid = threadIdx.x, lane = tid & 63, wave = tid >> 6;
  const int m = lane & 15, oct = lane >> 4;
  const float* ub = u + ((size_t)b * N + n0) * K;
  const float* tb = t + (size_t)b * O * K;
  const float nrm_inv = rsqrtf(fmaxf(sumsq[slot], 1e-12f));

  // ---- phase 1: bb = t . u^T ----
  const int mo = wave & 1, nt = wave >> 1;  // o-tile, n-tile
  f32x4 accb = {0.f, 0.f, 0.f, 0.f};
  for (int kc = 0; kc < K; kc += 64) {
    __syncthreads();
    {
      int r = tid >> 4, c4 = (tid & 15) * 4;  // t: 512 f4, 1/thread
      stage_hilo(t_hi, t_lo, r, c4, *(const float4*)&tb[(size_t)r * K + kc + c4]);
#pragma unroll
      for (int h = 0; h < 2; h++) {  // u: 1024 f4, 2/thread, hi only
        int i = tid + h * 512;
        int ur = i >> 4, uc = (i & 15) * 4;
        stage_hi(u_hi, ur, uc, *(const float4*)&ub[(size_t)ur * K + kc + uc]);
      }
    }
    __syncthreads();
#pragma unroll
    for (int ks = 0; ks < 64; ks += 32) {
      bf16x8 ah = frag_row(t_hi, mo * 16 + m, ks + oct * 8);
      bf16x8 al = frag_row(t_lo, mo * 16 + m, ks + oct * 8);
      bf16x8 bh = frag_row(u_hi, nt * 16 + m, ks + oct * 8);
      accb = __builtin_amdgcn_mfma_f32_16x16x32_bf16(ah, bh, accb, 0, 0, 0);
      accb = __builtin_amdgcn_mfma_f32_16x16x32_bf16(al, bh, accb, 0, 0, 0);
    }
  }
  __syncthreads();
#pragma unroll
  for (int r = 0; r < 4; r++)  // D: col=lane&15 (n), row=oct*4+r (o)
    wv[(mo * 16 + oct * 4 + r) * 68 + nt * 16 + m] = accb[r] * nrm_inv;
  __syncthreads();
  if (tid < 64) {  // softmax over o, column n=tid
    float mx = -1e30f;
    for (int o = 0; o < O; o++) mx = fmaxf(mx, wv[o * 68 + tid]);
    float s = 0.f;
    for (int o = 0; o < O; o++) { float e = __expf(wv[o * 68 + tid] - mx); wv[o * 68 + tid] = e; s += e; }
    float inv = 1.f / s;
    for (int o = 0; o < O; o++) wv[o * 68 + tid] *= inv;
  }
  __syncthreads();
  for (int i = tid; i < O * 64; i += 512) {  // Wv -> bf16 hi/lo, [o][ST], no swizzle
    int o = i >> 6, n = i & 63;
    unsigned int ph = pk_hi(wv[o * 68 + n], 0.f);
    float fx, fy;
    unpk(ph, fx, fy);
    unsigned int pl = pk_hi(wv[o * 68 + n] - fx, 0.f);
    wvh[o * ST + n] = (unsigned short)(ph & 0xffff);
    wvl[o * ST + n] = (unsigned short)(pl & 0xffff);
  }
  __syncthreads();

  // ---- phase 2: S += Wv . u  (k-red = n = 64 -> 2 MFMA steps) ----
  const int otile = wave & 1, ktile = wave >> 1;
  const int o0 = otile * 16;
  bf16x8 a_h[2], a_l[2];
#pragma unroll
  for (int s = 0; s < 2; s++) {  // A-frag: Wv[o0+m][s*32+oct*8 ..+8]
    a_h[s] = *(const bf16x8*)&wvh[(o0 + m) * ST + s * 32 + oct * 8];
    a_l[s] = *(const bf16x8*)&wvl[(o0 + m) * ST + s * 32 + oct * 8];
  }
  float* Sb = S + (size_t)b * O * K;
  for (int kc = 0; kc < K; kc += 64) {
    __syncthreads();
#pragma unroll
    for (int h = 0; h < 2; h++) {  // restage u chunk (L2/L3-hot re-read), hi only
      int i = tid + h * 512;
      int ur = i >> 4, uc = (i & 15) * 4;
      stage_hi(u_hi, ur, uc, *(const float4*)&ub[(size_t)ur * K + kc + uc]);
    }
    __syncthreads();
    f32x4 acs = {0.f, 0.f, 0.f, 0.f};
#pragma unroll
    for (int s = 0; s < 2; s++) {
      bf16x8 bh = frag_col(u_hi, ktile * 16 + m, s * 32 + oct * 8);
      acs = __builtin_amdgcn_mfma_f32_16x16x32_bf16(a_h[s], bh, acs, 0, 0, 0);
      acs = __builtin_amdgcn_mfma_f32_16x16x32_bf16(a_l[s], bh, acs, 0, 0, 0);
    }
#pragma unroll
    for (int r = 0; r < 4; r++)  // D: col=m -> kcol, row=oct*4+r -> o
      atomicAdd(&Sb[(size_t)(o0 + oct * 4 + r) * K + kc + ktile * 16 + m], acs[r]);
  }
}

extern "C" void kernel_launch(void* const* d_in, const int* in_sizes, int n_in,
                              void* d_out, int out_size, void* d_ws, size_t ws_size,
                              hipStream_t stream) {
  const float* u = (const float*)d_in[0];  // [B,N,K] f32
  const float* W = (const float*)d_in[1];  // [K,F] f32
  float* out = (float*)d_out;              // [B,O,D] f32

  float* ws = (float*)d_ws;
  float* S1 = ws;                           // B*O*K
  float* S2 = S1 + (size_t)B * O * K;       // B*O*K
  float* colsum = S2 + (size_t)B * O * K;   // B*K
  float* sumsq = colsum + (size_t)B * K;    // 16 (2 used)
  float* t = sumsq + 16;                    // B*O*K

  hipMemsetAsync(S1, 0, ((size_t)2 * B * O * K + B * K + 16) * sizeof(float), stream);

  k_colsum<<<dim3(B, 32), 256, 0, stream>>>(u, colsum);
  k_vjt<<<B * O, 512, 0, stream>>>(S1, colsum, W, sumsq, 0, t);   // iter0 (uniform)
  k_route<<<dim3(B, N / 64), 512, 0, stream>>>(t, u, sumsq, 0, S1);
  k_vjt<<<B * O, 512, 0, stream>>>(S1, colsum, W, sumsq, 1, t);   // iter1
  k_route<<<dim3(B, N / 64), 512, 0, stream>>>(t, u, sumsq, 1, S2);
  k_out<<<B * O, 512, 0, stream>>>(S2, W, out);                   // iter2 + squash
}

// Round 6
// 254.655 us; speedup vs baseline: 3.3068x; 1.0097x over previous
//
#include <hip/hip_runtime.h>
#include <hip/hip_bf16.h>

// Capsule routing; u_hat never materialized. Per iter:
//   vjt: vj = S@W_o -> global sumsq; t = W_o@vj (UNNORMALIZED)
//   route: bb = (t.u^T)/nrm -> softmax_o -> S' += Wv.u   (MFMA 16x16x32 bf16)
// fp32 via bf16 hi/lo split on t and Wv; u single bf16 (err ~2^-9, thr 1e-2).
// k_route keeps the whole u-tile (64n x 512k bf16, XOR-swizzled) resident in
// LDS: staged once, read row-wise in phase 1 and column-wise in phase 2.

constexpr int B = 32, N = 1024, K = 512, O = 32, D = 64, F = 2048;
constexpr int STU = 520;  // u_res row stride (u16): 1040B, 16B-aligned, stride%32dw=4
constexpr int ST2 = 72;   // t/wv row stride (u16)

typedef __attribute__((ext_vector_type(8))) short bf16x8;
typedef __attribute__((ext_vector_type(4))) float f32x4;

__device__ inline unsigned int pk_hi(float x, float y) {
  union { __hip_bfloat162 h; unsigned int u; } c;
  c.h = __float22bfloat162_rn(float2{x, y});
  return c.u;
}
__device__ inline unsigned short bf16_1(float x) {
  return (unsigned short)(pk_hi(x, 0.f) & 0xffffu);
}
__device__ inline void split2(float x, unsigned short& h, unsigned short& l) {
  h = bf16_1(x);
  l = bf16_1(x - __uint_as_float((unsigned int)h << 16));
}
__device__ inline float bf2f(unsigned short h) {
  return __uint_as_float((unsigned int)h << 16);
}
__device__ inline int swz(int r) { return ((r >> 3) & 7) << 3; }

// colsum[b,k] = (1/32) sum_n u[b,n,k]  (iter-0: softmax(0) uniform)
__global__ __launch_bounds__(256) void k_colsum(const float* __restrict__ u,
                                                float* __restrict__ cs) {
  int b = blockIdx.x, n0 = blockIdx.y * 32;
  int kq = (threadIdx.x & 127) * 4, ng = threadIdx.x >> 7;
  const float* ub = u + ((size_t)b * N + n0 + ng * 16) * K + kq;
  float4 a = {0.f, 0.f, 0.f, 0.f};
#pragma unroll
  for (int r = 0; r < 16; r++) {
    float4 v = *(const float4*)&ub[(size_t)r * K];
    a.x += v.x; a.y += v.y; a.z += v.z; a.w += v.w;
  }
  __shared__ float4 red[128];
  if (ng) red[threadIdx.x & 127] = a;
  __syncthreads();
  if (!ng) {
    float4 o = red[threadIdx.x];
    atomicAdd(&cs[b * K + kq + 0], (a.x + o.x) * (1.f / 32.f));
    atomicAdd(&cs[b * K + kq + 1], (a.y + o.y) * (1.f / 32.f));
    atomicAdd(&cs[b * K + kq + 2], (a.z + o.z) * (1.f / 32.f));
    atomicAdd(&cs[b * K + kq + 3], (a.w + o.w) * (1.f / 32.f));
  }
}

// vj[d]=sum_k s[k]W[k,o*64+d] -> sumsq atomic; t[k]=sum_d vj[d]W[k,o*64+d].
// t-phase: 8 lanes per W row (coalesced), shfl_xor reduce over the 8.
__global__ __launch_bounds__(512) void k_vjt(const float* __restrict__ S,
                                             const float* __restrict__ colsum,
                                             const float* __restrict__ W,
                                             float* __restrict__ sumsq, int slot,
                                             float* __restrict__ t) {
  __shared__ __align__(16) float s_s[K];
  __shared__ float red[7][D];
  __shared__ __align__(16) float vs[D];
  int bo = blockIdx.x, b = bo >> 5, o = bo & 31;
  int d = threadIdx.x & 63, ks = threadIdx.x >> 6;  // 8-way k split
  const float* src = (slot == 0) ? (colsum + (size_t)b * K) : (S + (size_t)bo * K);
  for (int i = threadIdx.x; i < K; i += 512) s_s[i] = src[i];
  __syncthreads();
  float acc = 0.f;
  const float* Wc = W + (size_t)o * D + d;
  for (int k = ks * 64; k < ks * 64 + 64; k += 4) {
    acc += s_s[k] * Wc[(size_t)k * F] + s_s[k + 1] * Wc[(size_t)(k + 1) * F] +
           s_s[k + 2] * Wc[(size_t)(k + 2) * F] + s_s[k + 3] * Wc[(size_t)(k + 3) * F];
  }
  if (ks) red[ks - 1][d] = acc;
  __syncthreads();
  if (ks == 0) {
#pragma unroll
    for (int j = 0; j < 7; j++) acc += red[j][d];
    vs[d] = acc;
    float ss = acc * acc;
#pragma unroll
    for (int m = 32; m >= 1; m >>= 1) ss += __shfl_xor(ss, m, 64);
    if (d == 0) atomicAdd(&sumsq[slot], ss);
  }
  __syncthreads();
  {  // t phase: wave handles 64 rows, 8 lanes/row
    int wave = threadIdx.x >> 6, lane = threadIdx.x & 63;
    int rr = lane >> 3, dc = lane & 7;
    float4 va = *(const float4*)&vs[dc * 8];
    float4 vb = *(const float4*)&vs[dc * 8 + 4];
#pragma unroll
    for (int i = 0; i < 8; i++) {
      int kk = wave * 64 + i * 8 + rr;
      const float* Wr = W + (size_t)kk * F + o * 64 + dc * 8;
      float4 wa = *(const float4*)Wr;
      float4 wb = *(const float4*)(Wr + 4);
      float p = wa.x * va.x + wa.y * va.y + wa.z * va.z + wa.w * va.w +
                wb.x * vb.x + wb.y * vb.y + wb.z * vb.z + wb.w * vb.w;
      p += __shfl_xor(p, 1, 64);
      p += __shfl_xor(p, 2, 64);
      p += __shfl_xor(p, 4, 64);
      if (dc == 0) t[(size_t)bo * K + kk] = p;
    }
  }
}

// Final: vj from S row -> squash -> out
__global__ __launch_bounds__(512) void k_out(const float* __restrict__ S,
                                             const float* __restrict__ W,
                                             float* __restrict__ out) {
  __shared__ __align__(16) float s_s[K];
  __shared__ float red[7][D];
  int bo = blockIdx.x, o = bo & 31;
  int d = threadIdx.x & 63, ks = threadIdx.x >> 6;
  const float* src = S + (size_t)bo * K;
  for (int i = threadIdx.x; i < K; i += 512) s_s[i] = src[i];
  __syncthreads();
  float acc = 0.f;
  const float* Wc = W + (size_t)o * D + d;
  for (int k = ks * 64; k < ks * 64 + 64; k += 4) {
    acc += s_s[k] * Wc[(size_t)k * F] + s_s[k + 1] * Wc[(size_t)(k + 1) * F] +
           s_s[k + 2] * Wc[(size_t)(k + 2) * F] + s_s[k + 3] * Wc[(size_t)(k + 3) * F];
  }
  if (ks) red[ks - 1][d] = acc;
  __syncthreads();
  if (ks == 0) {
#pragma unroll
    for (int j = 0; j < 7; j++) acc += red[j][d];
    float ss = acc * acc;
#pragma unroll
    for (int m = 32; m >= 1; m >>= 1) ss += __shfl_xor(ss, m, 64);
    float s = ss + 1e-7f;
    out[(size_t)bo * D + d] = (sqrtf(s) / (0.5f + s)) * acc;
  }
}

// Fused routing step, 64-n tile, 512 thr (8 waves), 2 blocks/CU.
// u-tile resident in LDS (bf16, swizzled). phase1: bb=(t.u^T)/nrm per k-chunk
// (t staged hi/lo per chunk). softmax over o on hi/lo logits. phase2: S+=Wv.u
// straight from resident u (no staging, no barriers).
__global__ __launch_bounds__(512, 4) void k_route(const float* __restrict__ t,
                                                  const float* __restrict__ u,
                                                  const float* __restrict__ sumsq,
                                                  int slot, float* __restrict__ S) {
  __shared__ unsigned short u_res[64 * STU];               // 66560 B
  __shared__ unsigned short t_hi[32 * ST2], t_lo[32 * ST2];  // 2x4608 B
  unsigned short* wvh = t_hi;  // alias: t dead after phase 1
  unsigned short* wvl = t_lo;

  const int b = blockIdx.x, n0 = blockIdx.y * 64;
  const int tid = threadIdx.x, lane = tid & 63, wave = tid >> 6;
  const int m = lane & 15, oct = lane >> 4;
  const float* ub = u + ((size_t)b * N + n0) * K;
  const float* tb = t + (size_t)b * O * K;
  const float nrm_inv = rsqrtf(fmaxf(sumsq[slot], 1e-12f));

  // ---- stage full u-tile: 64 rows x 512 cols, bf16 hi, XOR-swizzled ----
#pragma unroll
  for (int h = 0; h < 16; h++) {
    int i = tid + h * 512;      // 8192 float4 slots
    int r = i >> 7, c4 = (i & 127) * 4;
    float4 v = *(const float4*)&ub[(size_t)r * K + c4];
    uint2 p;
    p.x = pk_hi(v.x, v.y);
    p.y = pk_hi(v.z, v.w);
    *(uint2*)&u_res[r * STU + (c4 ^ swz(r))] = p;
  }

  // ---- phase 1: bb = t . u^T  (chunked over k for t staging) ----
  const int mo = wave & 1, nt = wave >> 1;  // o-half, n-quarter
  f32x4 accb = {0.f, 0.f, 0.f, 0.f};
  for (int kc = 0; kc < K; kc += 64) {
    __syncthreads();
    {  // stage t chunk hi/lo: 32 rows x 64 cols, 1 float4/thread
      int r = tid >> 4, c4 = (tid & 15) * 4;
      float4 tv = *(const float4*)&tb[(size_t)r * K + kc + c4];
      uint2 ph, pl;
      ph.x = pk_hi(tv.x, tv.y);
      ph.y = pk_hi(tv.z, tv.w);
      pl.x = pk_hi(tv.x - __uint_as_float(ph.x << 16),
                   tv.y - __uint_as_float(ph.x & 0xffff0000u));
      pl.y = pk_hi(tv.z - __uint_as_float(ph.y << 16),
                   tv.w - __uint_as_float(ph.y & 0xffff0000u));
      *(uint2*)&t_hi[r * ST2 + c4] = ph;
      *(uint2*)&t_lo[r * ST2 + c4] = pl;
    }
    __syncthreads();
#pragma unroll
    for (int ks = 0; ks < 64; ks += 32) {
      bf16x8 ah = *(const bf16x8*)&t_hi[(mo * 16 + m) * ST2 + ks + oct * 8];
      bf16x8 al = *(const bf16x8*)&t_lo[(mo * 16 + m) * ST2 + ks + oct * 8];
      int ur = nt * 16 + m;
      int kk = (kc + ks + oct * 8) ^ swz(ur);
      bf16x8 bh = *(const bf16x8*)&u_res[ur * STU + kk];
      accb = __builtin_amdgcn_mfma_f32_16x16x32_bf16(ah, bh, accb, 0, 0, 0);
      accb = __builtin_amdgcn_mfma_f32_16x16x32_bf16(al, bh, accb, 0, 0, 0);
    }
  }
  __syncthreads();  // t region dead; write logits hi/lo into it
#pragma unroll
  for (int r = 0; r < 4; r++) {  // D: col=m (n), row=oct*4+r (o)
    float val = accb[r] * nrm_inv;
    int o = mo * 16 + oct * 4 + r, n = nt * 16 + m;
    unsigned short h, l;
    split2(val, h, l);
    wvh[o * ST2 + n] = h;
    wvl[o * ST2 + n] = l;
  }
  __syncthreads();
  if (tid < 64) {  // softmax over o, column n=tid (hi/lo reconstructed fp32)
    float v[O];
    float mx = -1e30f;
#pragma unroll
    for (int o = 0; o < O; o++) {
      v[o] = bf2f(wvh[o * ST2 + tid]) + bf2f(wvl[o * ST2 + tid]);
      mx = fmaxf(mx, v[o]);
    }
    float s = 0.f;
#pragma unroll
    for (int o = 0; o < O; o++) { v[o] = __expf(v[o] - mx); s += v[o]; }
    float inv = 1.f / s;
#pragma unroll
    for (int o = 0; o < O; o++) {
      unsigned short h, l;
      split2(v[o] * inv, h, l);
      wvh[o * ST2 + tid] = h;
      wvl[o * ST2 + tid] = l;
    }
  }
  __syncthreads();

  // ---- phase 2: S += Wv . u  (resident u, no barriers) ----
  const int otile = wave & 1, ktile = wave >> 1;
  const int o0 = otile * 16;
  bf16x8 a_h[2], a_l[2];
#pragma unroll
  for (int s = 0; s < 2; s++) {
    a_h[s] = *(const bf16x8*)&wvh[(o0 + m) * ST2 + s * 32 + oct * 8];
    a_l[s] = *(const bf16x8*)&wvl[(o0 + m) * ST2 + s * 32 + oct * 8];
  }
  float* Sb = S + (size_t)b * O * K;
  for (int kc = 0; kc < K; kc += 64) {
    int kcol = kc + ktile * 16 + m;
    f32x4 acs = {0.f, 0.f, 0.f, 0.f};
#pragma unroll
    for (int s = 0; s < 2; s++) {
      bf16x8 bh;
#pragma unroll
      for (int j = 0; j < 8; j++) {
        int n = s * 32 + oct * 8 + j;
        bh[j] = (short)u_res[n * STU + (kcol ^ swz(n))];
      }
      acs = __builtin_amdgcn_mfma_f32_16x16x32_bf16(a_h[s], bh, acs, 0, 0, 0);
      acs = __builtin_amdgcn_mfma_f32_16x16x32_bf16(a_l[s], bh, acs, 0, 0, 0);
    }
#pragma unroll
    for (int r = 0; r < 4; r++)  // D: col=m -> kcol, row=oct*4+r -> o
      atomicAdd(&Sb[(size_t)(o0 + oct * 4 + r) * K + kcol], acs[r]);
  }
}

extern "C" void kernel_launch(void* const* d_in, const int* in_sizes, int n_in,
                              void* d_out, int out_size, void* d_ws, size_t ws_size,
                              hipStream_t stream) {
  const float* u = (const float*)d_in[0];  // [B,N,K] f32
  const float* W = (const float*)d_in[1];  // [K,F] f32
  float* out = (float*)d_out;              // [B,O,D] f32

  float* ws = (float*)d_ws;
  float* S1 = ws;                           // B*O*K
  float* S2 = S1 + (size_t)B * O * K;       // B*O*K
  float* colsum = S2 + (size_t)B * O * K;   // B*K
  float* sumsq = colsum + (size_t)B * K;    // 16 (2 used)
  float* t = sumsq + 16;                    // B*O*K

  hipMemsetAsync(S1, 0, ((size_t)2 * B * O * K + B * K + 16) * sizeof(float), stream);

  k_colsum<<<dim3(B, 32), 256, 0, stream>>>(u, colsum);
  k_vjt<<<B * O, 512, 0, stream>>>(S1, colsum, W, sumsq, 0, t);   // iter0 (uniform)
  k_route<<<dim3(B, N / 64), 512, 0, stream>>>(t, u, sumsq, 0, S1);
  k_vjt<<<B * O, 512, 0, stream>>>(S1, colsum, W, sumsq, 1, t);   // iter1
  k_route<<<dim3(B, N / 64), 512, 0, stream>>>(t, u, sumsq, 1, S2);
  k_out<<<B * O, 512, 0, stream>>>(S2, W, out);                   // iter2 + squash
}